// Round 15
// baseline (121.908 us; speedup 1.0000x reference)
//
#include <hip/hip_runtime.h>
#include <hip/hip_bf16.h>

#define NL 16
#define HID 16
#define LAT 64
#define BATCHN 262144

typedef __attribute__((ext_vector_type(4))) float f32x4;
typedef __attribute__((ext_vector_type(8))) short b16x8;

// gfx950-verified MFMA (guide §3 / m89): lane 16g+c holds A[row=c][k=8g+j],
// B[k=8g+j][col=c]; D reg j = D[row=4g+j][col=c].
__device__ __forceinline__ f32x4 MFMA32(b16x8 a, b16x8 b, f32x4 c) {
  return __builtin_amdgcn_mfma_f32_16x16x32_bf16(a, b, c, 0, 0, 0);
}

// RNE pair-pack via the official intrinsic (round 9+: passes, no asm hazards)
__device__ __forceinline__ unsigned pk2(float lo, float hi) {
  __hip_bfloat162 h2 = __float22bfloat162_rn(float2{lo, hi});
  union { __hip_bfloat162 h; unsigned u; } u; u.h = h2; return u.u;
}

#if __has_builtin(__builtin_amdgcn_exp2f)
__device__ __forceinline__ float fexp2(float x) { return __builtin_amdgcn_exp2f(x); }
#else
__device__ __forceinline__ float fexp2(float x) { return __expf(0.6931471805599453f * x); }
#endif
#if __has_builtin(__builtin_amdgcn_rcpf)
__device__ __forceinline__ float frcp(float x) { return __builtin_amdgcn_rcpf(x); }
#else
__device__ __forceinline__ float frcp(float x) { return __fdividef(1.f, x); }
#endif

__device__ __forceinline__ short bfs(float f) {
  union { __hip_bfloat16 h; short s; } u; u.h = __float2bfloat16(f); return u.s;
}
__device__ __forceinline__ float leaky(float v) { return fmaxf(v, 0.01f * v); }
#define TWO_LOG2E 2.885390081777927f   /* 2/ln2 = 2*log2(e) */

// e^u on [-1,1] (degree-6, rel err <= ~5e-4 at the ends): replaces one exp2
// (trans @ ~16cyc) with 6 fma (VALU @ 2cyc each) on the binding pipe.
__device__ __forceinline__ float exp_u(float u) {
  float p = 1.3888889e-3f;            // 1/720
  p = fmaf(p, u, 8.3333333e-3f);      // 1/120
  p = fmaf(p, u, 4.1666667e-2f);      // 1/24
  p = fmaf(p, u, 1.6666667e-1f);      // 1/6
  p = fmaf(p, u, 0.5f);
  p = fmaf(p, u, 1.0f);
  p = fmaf(p, u, 1.0f);
  return p;
}

// ---------------- setup: bake per-(layer,lane) fragments into d_ws ----------------
// s-net GEMM2 fragments (A2S, C2S) PRE-SCALED by 2*log2(e): w = exp2(ds) directly.
__global__ void prep_frags(
    const float* __restrict__ sW1, const float* __restrict__ sb1,
    const float* __restrict__ sW2, const float* __restrict__ sb2,
    const float* __restrict__ tW1, const float* __restrict__ tb1,
    const float* __restrict__ tW2, const float* __restrict__ tb2,
    b16x8* __restrict__ A1S, b16x8* __restrict__ A1T,
    b16x8* __restrict__ A2S, b16x8* __restrict__ A2T,
    f32x4* __restrict__ B1S, f32x4* __restrict__ B1T,
    f32x4* __restrict__ C2S, f32x4* __restrict__ C2T)
{
  const int l = blockIdx.x;
  const int lane = threadIdx.x;
  const int c = lane & 15, g = lane >> 4;
  const int PR = l & 1, PW = 1 - PR;
  const int idx = l * 64 + lane;

  b16x8 a;
  const float* w = sW1 + (l * HID + c) * LAT;
#pragma unroll
  for (int u = 0; u < 8; ++u) a[u] = bfs(w[16 * g + 2 * u + PR]);
  A1S[idx] = a;
  w = tW1 + (l * HID + c) * LAT;
#pragma unroll
  for (int u = 0; u < 8; ++u) a[u] = bfs(w[16 * g + 2 * u + PR]);
  A1T[idx] = a;
  B1S[idx] = ((const f32x4*)(sb1 + l * HID))[g];
  B1T[idx] = ((const f32x4*)(tb1 + l * HID))[g];

#pragma unroll
  for (int to = 0; to < 2; ++to) {
    const int m = 8 * (c >> 2) + 4 * to + (c & 3);
    const int d = 2 * m + PW;
    const int i2 = (l * 2 + to) * 64 + lane;
    b16x8 as = {0, 0, 0, 0, 0, 0, 0, 0}, at = {0, 0, 0, 0, 0, 0, 0, 0};
    const float* w2 = sW2 + (l * LAT + d) * HID + 4 * g;
#pragma unroll
    for (int j = 0; j < 4; ++j) as[j] = bfs(TWO_LOG2E * w2[j]);   // prescaled
    w2 = tW2 + (l * LAT + d) * HID + 4 * g;
#pragma unroll
    for (int j = 0; j < 4; ++j) at[4 + j] = bfs(w2[j]);
    A2S[i2] = as;
    A2T[i2] = at;
    f32x4 cs, ct;
#pragma unroll
    for (int j = 0; j < 4; ++j) {
      cs[j] = TWO_LOG2E * sb2[l * LAT + 16 * g + 8 * to + 2 * j + PW];  // prescaled
      ct[j] = tb2[l * LAT + 16 * g + 8 * to + 2 * j + PW];
    }
    C2S[i2] = cs;
    C2T[i2] = ct;
  }
}

// ---------------- main: one coupling layer, T=4 batch tiles (64 rows/wave) ------
// zst[T][p][uh][j] = z[row=rowbase+16T+c][dim = 16g + 2*(4uh+j) + p]  (f32)
// GEMM1 B-operand packed on-read (no bf16 shadow state: saves 32 VGPR at T=4).
// ds prescaled; w=exp2(ds); r=rcp(w+1); u=1-2r (=tanh); scale=e^u via poly;
// ld = 512 - 2*sum(r). HW saturation: w->inf => r=0,u=1; w->0 => r=1,u=-1.
template<int PR>
__device__ __forceinline__ void layer_step(
    const b16x8* __restrict__ A1S, const b16x8* __restrict__ A1T,
    const b16x8* __restrict__ A2S, const b16x8* __restrict__ A2T,
    const f32x4* __restrict__ B1S, const f32x4* __restrict__ B1T,
    const f32x4* __restrict__ C2S, const f32x4* __restrict__ C2T,
    int l, int lane,
    f32x4 (&zst)[4][2][2], float (&rsum)[4][2])
{
  constexpr int PW = 1 - PR;
  const int i1 = l * 64 + lane, i2 = (2 * l) * 64 + lane;
  const b16x8 a1s  = A1S[i1];
  const b16x8 a1t  = A1T[i1];
  const f32x4 b1s  = B1S[i1];
  const f32x4 b1t  = B1T[i1];
  const b16x8 a2s0 = A2S[i2];
  const b16x8 a2s1 = A2S[i2 + 64];
  const b16x8 a2t0 = A2T[i2];
  const b16x8 a2t1 = A2T[i2 + 64];
  const f32x4 c2s0 = C2S[i2];
  const f32x4 c2s1 = C2S[i2 + 64];
  const f32x4 c2t0 = C2T[i2];
  const f32x4 c2t1 = C2T[i2 + 64];

#pragma unroll
  for (int T = 0; T < 4; ++T) {
    union { unsigned u[4]; b16x8 v; } zB;   // pack-on-read B-operand
    zB.u[0] = pk2(zst[T][PR][0][0], zst[T][PR][0][1]);
    zB.u[1] = pk2(zst[T][PR][0][2], zst[T][PR][0][3]);
    zB.u[2] = pk2(zst[T][PR][1][0], zst[T][PR][1][1]);
    zB.u[3] = pk2(zst[T][PR][1][2], zst[T][PR][1][3]);
    const f32x4 hs = MFMA32(a1s, zB.v, b1s);
    const f32x4 ht = MFMA32(a1t, zB.v, b1t);
    union { unsigned u[4]; b16x8 v; } hc;   // [LeakyReLU(Hs) | LeakyReLU(Ht)]
    hc.u[0] = pk2(leaky(hs[0]), leaky(hs[1]));
    hc.u[1] = pk2(leaky(hs[2]), leaky(hs[3]));
    hc.u[2] = pk2(leaky(ht[0]), leaky(ht[1]));
    hc.u[3] = pk2(leaky(ht[2]), leaky(ht[3]));
    const f32x4 ds0 = MFMA32(a2s0, hc.v, c2s0);
    const f32x4 dt0 = MFMA32(a2t0, hc.v, c2t0);
    const f32x4 ds1 = MFMA32(a2s1, hc.v, c2s1);
    const f32x4 dt1 = MFMA32(a2t1, hc.v, c2t1);
#pragma unroll
    for (int j = 0; j < 4; ++j) {
      const float w0 = fexp2(ds0[j]);
      const float r0 = frcp(w0 + 1.f);
      rsum[T][0] += r0;
      const float u0 = fmaf(-2.f, r0, 1.f);
      zst[T][PW][0][j] = fmaf(zst[T][PW][0][j], exp_u(u0), dt0[j]);
      const float w1 = fexp2(ds1[j]);
      const float r1 = frcp(w1 + 1.f);
      rsum[T][1] += r1;
      const float u1 = fmaf(-2.f, r1, 1.f);
      zst[T][PW][1][j] = fmaf(zst[T][PW][1][j], exp_u(u1), dt1[j]);
    }
  }
}

// 1-wave WGs (fine dispatch granularity), 64 rows/wave: 4 independent
// T-chains per wave to raise VALU+trans pipe utilization.
__global__ __launch_bounds__(64) void realnvp_fwd(
    const float* __restrict__ x, float* __restrict__ out,
    const b16x8* __restrict__ A1S, const b16x8* __restrict__ A1T,
    const b16x8* __restrict__ A2S, const b16x8* __restrict__ A2T,
    const f32x4* __restrict__ B1S, const f32x4* __restrict__ B1T,
    const f32x4* __restrict__ C2S, const f32x4* __restrict__ C2T)
{
  const int lane = threadIdx.x;          // 0..63
  const int c = lane & 15, g = lane >> 4;
  const int rowbase = blockIdx.x * 64;   // 64 rows per wave (T=4 x 16)

  f32x4 zst[4][2][2];
  float rsum[4][2] = {{0.f,0.f},{0.f,0.f},{0.f,0.f},{0.f,0.f}};
#pragma unroll
  for (int T = 0; T < 4; ++T) {
    const f32x4* xr = (const f32x4*)(x + (size_t)(rowbase + T * 16 + c) * LAT);
    const f32x4 q0 = xr[4 * g], q1 = xr[4 * g + 1], q2 = xr[4 * g + 2], q3 = xr[4 * g + 3];
    zst[T][0][0] = (f32x4){q0[0], q0[2], q1[0], q1[2]};
    zst[T][1][0] = (f32x4){q0[1], q0[3], q1[1], q1[3]};
    zst[T][0][1] = (f32x4){q2[0], q2[2], q3[0], q3[2]};
    zst[T][1][1] = (f32x4){q2[1], q2[3], q3[1], q3[3]};
  }

#pragma unroll 1
  for (int lp = 0; lp < NL / 2; ++lp) {
    layer_step<0>(A1S, A1T, A2S, A2T, B1S, B1T, C2S, C2T, 2 * lp,     lane, zst, rsum);
    layer_step<1>(A1S, A1T, A2S, A2T, B1S, B1T, C2S, C2T, 2 * lp + 1, lane, zst, rsum);
  }

#pragma unroll
  for (int T = 0; T < 4; ++T) {
    f32x4* zo = (f32x4*)(out + (size_t)(rowbase + T * 16 + c) * LAT);
    const f32x4 e0 = zst[T][0][0], o0 = zst[T][1][0];
    const f32x4 e1 = zst[T][0][1], o1 = zst[T][1][1];
    zo[4 * g]     = (f32x4){e0[0], o0[0], e0[1], o0[1]};
    zo[4 * g + 1] = (f32x4){e0[2], o0[2], e0[3], o0[3]};
    zo[4 * g + 2] = (f32x4){e1[0], o1[0], e1[1], o1[1]};
    zo[4 * g + 3] = (f32x4){e1[2], o1[2], e1[3], o1[3]};
  }
  // ld = 512 - 2*sum(r); reduce partials across g-groups, lane-group g writes tile g
  float ldv[4];
#pragma unroll
  for (int T = 0; T < 4; ++T) {
    float rs = rsum[T][0] + rsum[T][1];
    rs += __shfl_xor(rs, 16, 64);
    rs += __shfl_xor(rs, 32, 64);
    ldv[T] = fmaf(-2.f, rs, 512.f);
  }
  const float lo = (g & 1) ? ldv[1] : ldv[0];
  const float hi = (g & 1) ? ldv[3] : ldv[2];
  out[(size_t)BATCHN * LAT + rowbase + g * 16 + c] = (g & 2) ? hi : lo;
}

extern "C" void kernel_launch(void* const* d_in, const int* in_sizes, int n_in,
                              void* d_out, int out_size, void* d_ws, size_t ws_size,
                              hipStream_t stream) {
  const float* x   = (const float*)d_in[0];
  const float* sW1 = (const float*)d_in[1];
  const float* sb1 = (const float*)d_in[2];
  const float* sW2 = (const float*)d_in[3];
  const float* sb2 = (const float*)d_in[4];
  const float* tW1 = (const float*)d_in[5];
  const float* tb1 = (const float*)d_in[6];
  const float* tW2 = (const float*)d_in[7];
  const float* tb2 = (const float*)d_in[8];
  float* out = (float*)d_out;

  char* w = (char*)d_ws;
  b16x8* A1S = (b16x8*)w;            w += NL * 64 * sizeof(b16x8);
  b16x8* A1T = (b16x8*)w;            w += NL * 64 * sizeof(b16x8);
  b16x8* A2S = (b16x8*)w;            w += NL * 128 * sizeof(b16x8);
  b16x8* A2T = (b16x8*)w;            w += NL * 128 * sizeof(b16x8);
  f32x4* B1S = (f32x4*)w;            w += NL * 64 * sizeof(f32x4);
  f32x4* B1T = (f32x4*)w;            w += NL * 64 * sizeof(f32x4);
  f32x4* C2S = (f32x4*)w;            w += NL * 128 * sizeof(f32x4);
  f32x4* C2T = (f32x4*)w;            w += NL * 128 * sizeof(f32x4);

  hipLaunchKernelGGL(prep_frags, dim3(NL), dim3(64), 0, stream,
                     sW1, sb1, sW2, sb2, tW1, tb1, tW2, tb2,
                     A1S, A1T, A2S, A2T, B1S, B1T, C2S, C2T);
  hipLaunchKernelGGL(realnvp_fwd, dim3(BATCHN / 64), dim3(64), 0, stream,
                     x, out, A1S, A1T, A2S, A2T, B1S, B1T, C2S, C2T);
}

// Round 16
// 113.778 us; speedup vs baseline: 1.0715x; 1.0715x over previous
//
#include <hip/hip_runtime.h>
#include <hip/hip_bf16.h>

#define NL 16
#define HID 16
#define LAT 64
#define BATCHN 262144

typedef __attribute__((ext_vector_type(4))) float f32x4;
typedef __attribute__((ext_vector_type(8))) short b16x8;

// gfx950-verified MFMA (guide §3 / m89): lane 16g+c holds A[row=c][k=8g+j],
// B[k=8g+j][col=c]; D reg j = D[row=4g+j][col=c].
__device__ __forceinline__ f32x4 MFMA32(b16x8 a, b16x8 b, f32x4 c) {
  return __builtin_amdgcn_mfma_f32_16x16x32_bf16(a, b, c, 0, 0, 0);
}

// RNE pair-pack via the official intrinsic (round 9+: passes, no asm hazards)
__device__ __forceinline__ unsigned pk2(float lo, float hi) {
  __hip_bfloat162 h2 = __float22bfloat162_rn(float2{lo, hi});
  union { __hip_bfloat162 h; unsigned u; } u; u.h = h2; return u.u;
}

#if __has_builtin(__builtin_amdgcn_exp2f)
__device__ __forceinline__ float fexp2(float x) { return __builtin_amdgcn_exp2f(x); }
#else
__device__ __forceinline__ float fexp2(float x) { return __expf(0.6931471805599453f * x); }
#endif
#if __has_builtin(__builtin_amdgcn_rcpf)
__device__ __forceinline__ float frcp(float x) { return __builtin_amdgcn_rcpf(x); }
#else
__device__ __forceinline__ float frcp(float x) { return __fdividef(1.f, x); }
#endif
#if __has_builtin(__builtin_amdgcn_sched_barrier)
#define SCHED_PIN() __builtin_amdgcn_sched_barrier(0)
#else
#define SCHED_PIN()
#endif

__device__ __forceinline__ short bfs(float f) {
  union { __hip_bfloat16 h; short s; } u; u.h = __float2bfloat16(f); return u.s;
}
__device__ __forceinline__ float leaky(float v) { return fmaxf(v, 0.01f * v); }
#define TWO_LOG2E 2.885390081777927f   /* 2/ln2 = 2*log2(e) */

// e^v on [-0.5, 0.5]: degree-5 Taylor, rel err <= 2e-5. Used as (e^{0.5-r})^2
// = e^{1-2r} = e^{tanh} -> replaces one exp2 (trans) with 5 fma + 1 mul (VALU).
__device__ __forceinline__ float expq(float v) {
  float p = 8.3333333e-3f;            // 1/120
  p = fmaf(p, v, 4.1666667e-2f);      // 1/24
  p = fmaf(p, v, 1.6666667e-1f);      // 1/6
  p = fmaf(p, v, 0.5f);
  p = fmaf(p, v, 1.0f);
  p = fmaf(p, v, 1.0f);
  return p;
}

// ---------------- setup: bake per-(layer,lane) fragments into d_ws ----------------
// s-net GEMM2 fragments (A2S, C2S) PRE-SCALED by 2*log2(e): w = exp2(ds) directly.
__global__ void prep_frags(
    const float* __restrict__ sW1, const float* __restrict__ sb1,
    const float* __restrict__ sW2, const float* __restrict__ sb2,
    const float* __restrict__ tW1, const float* __restrict__ tb1,
    const float* __restrict__ tW2, const float* __restrict__ tb2,
    b16x8* __restrict__ A1S, b16x8* __restrict__ A1T,
    b16x8* __restrict__ A2S, b16x8* __restrict__ A2T,
    f32x4* __restrict__ B1S, f32x4* __restrict__ B1T,
    f32x4* __restrict__ C2S, f32x4* __restrict__ C2T)
{
  const int l = blockIdx.x;
  const int lane = threadIdx.x;
  const int c = lane & 15, g = lane >> 4;
  const int PR = l & 1, PW = 1 - PR;
  const int idx = l * 64 + lane;

  b16x8 a;
  const float* w = sW1 + (l * HID + c) * LAT;
#pragma unroll
  for (int u = 0; u < 8; ++u) a[u] = bfs(w[16 * g + 2 * u + PR]);
  A1S[idx] = a;
  w = tW1 + (l * HID + c) * LAT;
#pragma unroll
  for (int u = 0; u < 8; ++u) a[u] = bfs(w[16 * g + 2 * u + PR]);
  A1T[idx] = a;
  B1S[idx] = ((const f32x4*)(sb1 + l * HID))[g];
  B1T[idx] = ((const f32x4*)(tb1 + l * HID))[g];

#pragma unroll
  for (int to = 0; to < 2; ++to) {
    const int m = 8 * (c >> 2) + 4 * to + (c & 3);
    const int d = 2 * m + PW;
    const int i2 = (l * 2 + to) * 64 + lane;
    b16x8 as = {0, 0, 0, 0, 0, 0, 0, 0}, at = {0, 0, 0, 0, 0, 0, 0, 0};
    const float* w2 = sW2 + (l * LAT + d) * HID + 4 * g;
#pragma unroll
    for (int j = 0; j < 4; ++j) as[j] = bfs(TWO_LOG2E * w2[j]);   // prescaled
    w2 = tW2 + (l * LAT + d) * HID + 4 * g;
#pragma unroll
    for (int j = 0; j < 4; ++j) at[4 + j] = bfs(w2[j]);
    A2S[i2] = as;
    A2T[i2] = at;
    f32x4 cs, ct;
#pragma unroll
    for (int j = 0; j < 4; ++j) {
      cs[j] = TWO_LOG2E * sb2[l * LAT + 16 * g + 8 * to + 2 * j + PW];  // prescaled
      ct[j] = tb2[l * LAT + 16 * g + 8 * to + 2 * j + PW];
    }
    C2S[i2] = cs;
    C2T[i2] = ct;
  }
}

// Per-layer fragment bundle (register prefetch unit): 12 dwordx4 loads.
struct FR {
  b16x8 a1s, a1t, a2s0, a2s1, a2t0, a2t1;
  f32x4 b1s, b1t, c2s0, c2s1, c2t0, c2t1;
};

__device__ __forceinline__ FR ldfr(
    const b16x8* __restrict__ A1S, const b16x8* __restrict__ A1T,
    const b16x8* __restrict__ A2S, const b16x8* __restrict__ A2T,
    const f32x4* __restrict__ B1S, const f32x4* __restrict__ B1T,
    const f32x4* __restrict__ C2S, const f32x4* __restrict__ C2T,
    int l, int lane)
{
  FR f;
  const int i1 = l * 64 + lane, i2 = (2 * l) * 64 + lane;
  f.a1s  = A1S[i1];      f.a1t  = A1T[i1];
  f.a2s0 = A2S[i2];      f.a2s1 = A2S[i2 + 64];
  f.a2t0 = A2T[i2];      f.a2t1 = A2T[i2 + 64];
  f.b1s  = B1S[i1];      f.b1t  = B1T[i1];
  f.c2s0 = C2S[i2];      f.c2s1 = C2S[i2 + 64];
  f.c2t0 = C2T[i2];      f.c2t1 = C2T[i2 + 64];
  return f;
}

// ---------------- main: one coupling layer ----------------
// zst[T][p][uh][j] = z[row=rowbase+16T+c][dim = 16g + 2*(4uh+j) + p]  (f32)
// zbf[T][p] = same 8 values bf16-packed = B-operand of GEMM1 (k=8g+u).
// ds prescaled by 2*log2(e); w=exp2(min(ds,30)); pairwise-batched rcp gives
// r0,r1 (exact to ~1e-6); ld = 512-2*sum(r); e^{tanh} = expq(0.5-r)^2.
template<int PR>
__device__ __forceinline__ void layer_step(
    const FR& f, f32x4 (&zst)[2][2][2], b16x8 (&zbf)[2][2], float (&rsum)[2][2])
{
  constexpr int PW = 1 - PR;
#pragma unroll
  for (int T = 0; T < 2; ++T) {
    const f32x4 hs = MFMA32(f.a1s, zbf[T][PR], f.b1s);
    const f32x4 ht = MFMA32(f.a1t, zbf[T][PR], f.b1t);
    union { unsigned u[4]; b16x8 v; } hc;   // [LeakyReLU(Hs) | LeakyReLU(Ht)]
    hc.u[0] = pk2(leaky(hs[0]), leaky(hs[1]));
    hc.u[1] = pk2(leaky(hs[2]), leaky(hs[3]));
    hc.u[2] = pk2(leaky(ht[0]), leaky(ht[1]));
    hc.u[3] = pk2(leaky(ht[2]), leaky(ht[3]));
    const f32x4 ds0 = MFMA32(f.a2s0, hc.v, f.c2s0);
    const f32x4 dt0 = MFMA32(f.a2t0, hc.v, f.c2t0);
    const f32x4 ds1 = MFMA32(f.a2s1, hc.v, f.c2s1);
    const f32x4 dt1 = MFMA32(f.a2t1, hc.v, f.c2t1);
    f32x4 z0 = zst[T][PW][0], z1 = zst[T][PW][1];
#pragma unroll
    for (int j = 0; j < 4; ++j) {
      // Pair (ds0[j], ds1[j]): 2 exp2 + 1 rcp for both elements.
      // clamp at 30: tanh(10.4)=1 to fp32; keeps a*b < 2^61 finite (no 0*inf).
      const float w0 = fexp2(fminf(ds0[j], 30.f));
      const float w1 = fexp2(fminf(ds1[j], 30.f));
      const float av = w0 + 1.f, bv = w1 + 1.f;
      const float rp = frcp(av * bv);
      const float r0 = rp * bv;
      const float r1 = rp * av;
      rsum[T][0] += r0;
      rsum[T][1] += r1;
      // e^{tanh} = e^{1-2r} = (e^{0.5-r})^2, poly on [-0.5,0.5]
      const float p0 = expq(0.5f - r0);
      const float p1 = expq(0.5f - r1);
      z0[j] = fmaf(z0[j], p0 * p0, dt0[j]);
      z1[j] = fmaf(z1[j], p1 * p1, dt1[j]);
    }
    zst[T][PW][0] = z0;
    zst[T][PW][1] = z1;
    union { unsigned u[4]; b16x8 v; } nz;
    nz.u[0] = pk2(z0[0], z0[1]);
    nz.u[1] = pk2(z0[2], z0[3]);
    nz.u[2] = pk2(z1[0], z1[1]);
    nz.u[3] = pk2(z1[2], z1[3]);
    zbf[T][PW] = nz.v;
  }
}

__global__ __launch_bounds__(64) void realnvp_fwd(
    const float* __restrict__ x, float* __restrict__ out,
    const b16x8* __restrict__ A1S, const b16x8* __restrict__ A1T,
    const b16x8* __restrict__ A2S, const b16x8* __restrict__ A2T,
    const f32x4* __restrict__ B1S, const f32x4* __restrict__ B1T,
    const f32x4* __restrict__ C2S, const f32x4* __restrict__ C2T)
{
  const int lane = threadIdx.x;          // 0..63
  const int c = lane & 15, g = lane >> 4;
  const int rowbase = blockIdx.x * 32;   // 32 rows per wave (T=2 x 16)

  f32x4 zst[2][2][2];
  b16x8 zbf[2][2];
  float rsum[2][2] = {{0.f, 0.f}, {0.f, 0.f}};
#pragma unroll
  for (int T = 0; T < 2; ++T) {
    const f32x4* xr = (const f32x4*)(x + (size_t)(rowbase + T * 16 + c) * LAT);
    const f32x4 q0 = xr[4 * g], q1 = xr[4 * g + 1], q2 = xr[4 * g + 2], q3 = xr[4 * g + 3];
    zst[T][0][0] = (f32x4){q0[0], q0[2], q1[0], q1[2]};
    zst[T][1][0] = (f32x4){q0[1], q0[3], q1[1], q1[3]};
    zst[T][0][1] = (f32x4){q2[0], q2[2], q3[0], q3[2]};
    zst[T][1][1] = (f32x4){q2[1], q2[3], q3[1], q3[3]};
#pragma unroll
    for (int p = 0; p < 2; ++p) {
      union { unsigned u[4]; b16x8 v; } zb;
      zb.u[0] = pk2(zst[T][p][0][0], zst[T][p][0][1]);
      zb.u[1] = pk2(zst[T][p][0][2], zst[T][p][0][3]);
      zb.u[2] = pk2(zst[T][p][1][0], zst[T][p][1][1]);
      zb.u[3] = pk2(zst[T][p][1][2], zst[T][p][1][3]);
      zbf[T][p] = zb.v;
    }
  }

  // Pinned software pipeline (R14: verified by VGPR 68->116; keep).
  FR f0 = ldfr(A1S, A1T, A2S, A2T, B1S, B1T, C2S, C2T, 0, lane);
#pragma unroll 1
  for (int lp = 0; lp < NL / 2; ++lp) {
    FR f1 = ldfr(A1S, A1T, A2S, A2T, B1S, B1T, C2S, C2T, 2 * lp + 1, lane);
    SCHED_PIN();
    layer_step<0>(f0, zst, zbf, rsum);
    const int nxt = (lp == NL / 2 - 1) ? (NL - 1) : (2 * lp + 2);  // clamp (dead last iter)
    FR f2 = ldfr(A1S, A1T, A2S, A2T, B1S, B1T, C2S, C2T, nxt, lane);
    SCHED_PIN();
    layer_step<1>(f1, zst, zbf, rsum);
    f0 = f2;
  }

#pragma unroll
  for (int T = 0; T < 2; ++T) {
    f32x4* zo = (f32x4*)(out + (size_t)(rowbase + T * 16 + c) * LAT);
    const f32x4 e0 = zst[T][0][0], o0 = zst[T][1][0];
    const f32x4 e1 = zst[T][0][1], o1 = zst[T][1][1];
    zo[4 * g]     = (f32x4){e0[0], o0[0], e0[1], o0[1]};
    zo[4 * g + 1] = (f32x4){e0[2], o0[2], e0[3], o0[3]};
    zo[4 * g + 2] = (f32x4){e1[0], o1[0], e1[1], o1[1]};
    zo[4 * g + 3] = (f32x4){e1[2], o1[2], e1[3], o1[3]};
  }
  // ld = sum(1-2r) over 512 tanh terms per row = 512 - 2*sum(r)
  float ldv[2];
#pragma unroll
  for (int T = 0; T < 2; ++T) {
    float rs = rsum[T][0] + rsum[T][1];
    rs += __shfl_xor(rs, 16, 64);
    rs += __shfl_xor(rs, 32, 64);
    ldv[T] = fmaf(-2.f, rs, 512.f);
  }
  if (g < 2)
    out[(size_t)BATCHN * LAT + rowbase + g * 16 + c] = g ? ldv[1] : ldv[0];
}

extern "C" void kernel_launch(void* const* d_in, const int* in_sizes, int n_in,
                              void* d_out, int out_size, void* d_ws, size_t ws_size,
                              hipStream_t stream) {
  const float* x   = (const float*)d_in[0];
  const float* sW1 = (const float*)d_in[1];
  const float* sb1 = (const float*)d_in[2];
  const float* sW2 = (const float*)d_in[3];
  const float* sb2 = (const float*)d_in[4];
  const float* tW1 = (const float*)d_in[5];
  const float* tb1 = (const float*)d_in[6];
  const float* tW2 = (const float*)d_in[7];
  const float* tb2 = (const float*)d_in[8];
  float* out = (float*)d_out;

  char* w = (char*)d_ws;
  b16x8* A1S = (b16x8*)w;            w += NL * 64 * sizeof(b16x8);
  b16x8* A1T = (b16x8*)w;            w += NL * 64 * sizeof(b16x8);
  b16x8* A2S = (b16x8*)w;            w += NL * 128 * sizeof(b16x8);
  b16x8* A2T = (b16x8*)w;            w += NL * 128 * sizeof(b16x8);
  f32x4* B1S = (f32x4*)w;            w += NL * 64 * sizeof(f32x4);
  f32x4* B1T = (f32x4*)w;            w += NL * 64 * sizeof(f32x4);
  f32x4* C2S = (f32x4*)w;            w += NL * 128 * sizeof(f32x4);
  f32x4* C2T = (f32x4*)w;            w += NL * 128 * sizeof(f32x4);

  hipLaunchKernelGGL(prep_frags, dim3(NL), dim3(64), 0, stream,
                     sW1, sb1, sW2, sb2, tW1, tb1, tW2, tb2,
                     A1S, A1T, A2S, A2T, B1S, B1T, C2S, C2T);
  hipLaunchKernelGGL(realnvp_fwd, dim3(BATCHN / 32), dim3(64), 0, stream,
                     x, out, A1S, A1T, A2S, A2T, B1S, B1T, C2S, C2T);
}

// Round 17
// 103.212 us; speedup vs baseline: 1.1811x; 1.1024x over previous
//
#include <hip/hip_runtime.h>
#include <hip/hip_bf16.h>

#define NL 16
#define HID 16
#define LAT 64
#define BATCHN 262144

typedef __attribute__((ext_vector_type(4))) float f32x4;
typedef __attribute__((ext_vector_type(8))) short b16x8;

// gfx950-verified MFMA (guide §3 / m89): lane 16g+c holds A[row=c][k=8g+j],
// B[k=8g+j][col=c]; D reg j = D[row=4g+j][col=c].
__device__ __forceinline__ f32x4 MFMA32(b16x8 a, b16x8 b, f32x4 c) {
  return __builtin_amdgcn_mfma_f32_16x16x32_bf16(a, b, c, 0, 0, 0);
}

// RNE pair-pack via the official intrinsic (round 9+: passes, no asm hazards)
__device__ __forceinline__ unsigned pk2(float lo, float hi) {
  __hip_bfloat162 h2 = __float22bfloat162_rn(float2{lo, hi});
  union { __hip_bfloat162 h; unsigned u; } u; u.h = h2; return u.u;
}

#if __has_builtin(__builtin_amdgcn_exp2f)
__device__ __forceinline__ float fexp2(float x) { return __builtin_amdgcn_exp2f(x); }
#else
__device__ __forceinline__ float fexp2(float x) { return __expf(0.6931471805599453f * x); }
#endif
#if __has_builtin(__builtin_amdgcn_rcpf)
__device__ __forceinline__ float frcp(float x) { return __builtin_amdgcn_rcpf(x); }
#else
__device__ __forceinline__ float frcp(float x) { return __fdividef(1.f, x); }
#endif
#if __has_builtin(__builtin_amdgcn_sched_barrier)
#define SCHED_PIN() __builtin_amdgcn_sched_barrier(0)
#else
#define SCHED_PIN()
#endif

__device__ __forceinline__ short bfs(float f) {
  union { __hip_bfloat16 h; short s; } u; u.h = __float2bfloat16(f); return u.s;
}
__device__ __forceinline__ float leaky(float v) { return fmaxf(v, 0.01f * v); }
#define TWO_LOG2E 2.885390081777927f   /* 2/ln2 = 2*log2(e) */
#define LOG2E     1.442695040888963f

// ---------------- setup: bake per-(layer,lane) fragments into d_ws ----------------
// s-net GEMM2 fragments (A2S, C2S) PRE-SCALED by 2*log2(e): w = exp2(ds) directly.
__global__ void prep_frags(
    const float* __restrict__ sW1, const float* __restrict__ sb1,
    const float* __restrict__ sW2, const float* __restrict__ sb2,
    const float* __restrict__ tW1, const float* __restrict__ tb1,
    const float* __restrict__ tW2, const float* __restrict__ tb2,
    b16x8* __restrict__ A1S, b16x8* __restrict__ A1T,
    b16x8* __restrict__ A2S, b16x8* __restrict__ A2T,
    f32x4* __restrict__ B1S, f32x4* __restrict__ B1T,
    f32x4* __restrict__ C2S, f32x4* __restrict__ C2T)
{
  const int l = blockIdx.x;
  const int lane = threadIdx.x;
  const int c = lane & 15, g = lane >> 4;
  const int PR = l & 1, PW = 1 - PR;
  const int idx = l * 64 + lane;

  b16x8 a;
  const float* w = sW1 + (l * HID + c) * LAT;
#pragma unroll
  for (int u = 0; u < 8; ++u) a[u] = bfs(w[16 * g + 2 * u + PR]);
  A1S[idx] = a;
  w = tW1 + (l * HID + c) * LAT;
#pragma unroll
  for (int u = 0; u < 8; ++u) a[u] = bfs(w[16 * g + 2 * u + PR]);
  A1T[idx] = a;
  B1S[idx] = ((const f32x4*)(sb1 + l * HID))[g];
  B1T[idx] = ((const f32x4*)(tb1 + l * HID))[g];

#pragma unroll
  for (int to = 0; to < 2; ++to) {
    const int m = 8 * (c >> 2) + 4 * to + (c & 3);
    const int d = 2 * m + PW;
    const int i2 = (l * 2 + to) * 64 + lane;
    b16x8 as = {0, 0, 0, 0, 0, 0, 0, 0}, at = {0, 0, 0, 0, 0, 0, 0, 0};
    const float* w2 = sW2 + (l * LAT + d) * HID + 4 * g;
#pragma unroll
    for (int j = 0; j < 4; ++j) as[j] = bfs(TWO_LOG2E * w2[j]);   // prescaled
    w2 = tW2 + (l * LAT + d) * HID + 4 * g;
#pragma unroll
    for (int j = 0; j < 4; ++j) at[4 + j] = bfs(w2[j]);
    A2S[i2] = as;
    A2T[i2] = at;
    f32x4 cs, ct;
#pragma unroll
    for (int j = 0; j < 4; ++j) {
      cs[j] = TWO_LOG2E * sb2[l * LAT + 16 * g + 8 * to + 2 * j + PW];  // prescaled
      ct[j] = tb2[l * LAT + 16 * g + 8 * to + 2 * j + PW];
    }
    C2S[i2] = cs;
    C2T[i2] = ct;
  }
}

// Per-layer fragment bundle (register prefetch unit): 12 dwordx4 loads.
struct FR {
  b16x8 a1s, a1t, a2s0, a2s1, a2t0, a2t1;
  f32x4 b1s, b1t, c2s0, c2s1, c2t0, c2t1;
};

__device__ __forceinline__ FR ldfr(
    const b16x8* __restrict__ A1S, const b16x8* __restrict__ A1T,
    const b16x8* __restrict__ A2S, const b16x8* __restrict__ A2T,
    const f32x4* __restrict__ B1S, const f32x4* __restrict__ B1T,
    const f32x4* __restrict__ C2S, const f32x4* __restrict__ C2T,
    int l, int lane)
{
  FR f;
  const int i1 = l * 64 + lane, i2 = (2 * l) * 64 + lane;
  f.a1s  = A1S[i1];      f.a1t  = A1T[i1];
  f.a2s0 = A2S[i2];      f.a2s1 = A2S[i2 + 64];
  f.a2t0 = A2T[i2];      f.a2t1 = A2T[i2 + 64];
  f.b1s  = B1S[i1];      f.b1t  = B1T[i1];
  f.c2s0 = C2S[i2];      f.c2s1 = C2S[i2 + 64];
  f.c2t0 = C2T[i2];      f.c2t1 = C2T[i2 + 64];
  return f;
}

// ---------------- main: one coupling layer ----------------
// zst[T][p][uh][j] = z[row=rowbase+16T+c][dim = 16g + 2*(4uh+j) + p]  (f32)
// zbf[T][p] = same 8 values bf16-packed = B-operand of GEMM1 (k=8g+u).
// ds prescaled by 2*log2(e); r = 1/(exp2(ds)+1); ld = 512-2*sum(r).
// Per-element form (4 VALU + 3 trans) is the measured local optimum:
// both rebalances away from it (R12 batch-rcp, R16 poly) regressed.
template<int PR>
__device__ __forceinline__ void layer_step(
    const FR& f, f32x4 (&zst)[2][2][2], b16x8 (&zbf)[2][2], float (&rsum)[2][2])
{
  constexpr int PW = 1 - PR;
#pragma unroll
  for (int T = 0; T < 2; ++T) {
    const f32x4 hs = MFMA32(f.a1s, zbf[T][PR], f.b1s);
    const f32x4 ht = MFMA32(f.a1t, zbf[T][PR], f.b1t);
    union { unsigned u[4]; b16x8 v; } hc;   // [LeakyReLU(Hs) | LeakyReLU(Ht)]
    hc.u[0] = pk2(leaky(hs[0]), leaky(hs[1]));
    hc.u[1] = pk2(leaky(hs[2]), leaky(hs[3]));
    hc.u[2] = pk2(leaky(ht[0]), leaky(ht[1]));
    hc.u[3] = pk2(leaky(ht[2]), leaky(ht[3]));
    const f32x4 ds0 = MFMA32(f.a2s0, hc.v, f.c2s0);
    const f32x4 dt0 = MFMA32(f.a2t0, hc.v, f.c2t0);
    const f32x4 ds1 = MFMA32(f.a2s1, hc.v, f.c2s1);
    const f32x4 dt1 = MFMA32(f.a2t1, hc.v, f.c2t1);
    f32x4 z0 = zst[T][PW][0], z1 = zst[T][PW][1];
#pragma unroll
    for (int j = 0; j < 4; ++j) {
      // r = 1/(exp2(ds)+1) (ds prescaled); z' = z*exp2(LOG2E - TWO_LOG2E*r) + t
      const float w0 = fexp2(ds0[j]);
      const float r0 = frcp(w0 + 1.f);
      rsum[T][0] += r0;
      z0[j] = fmaf(z0[j], fexp2(fmaf(-TWO_LOG2E, r0, LOG2E)), dt0[j]);
      const float w1 = fexp2(ds1[j]);
      const float r1 = frcp(w1 + 1.f);
      rsum[T][1] += r1;
      z1[j] = fmaf(z1[j], fexp2(fmaf(-TWO_LOG2E, r1, LOG2E)), dt1[j]);
    }
    zst[T][PW][0] = z0;
    zst[T][PW][1] = z1;
    union { unsigned u[4]; b16x8 v; } nz;
    nz.u[0] = pk2(z0[0], z0[1]);
    nz.u[1] = pk2(z0[2], z0[3]);
    nz.u[2] = pk2(z1[0], z1[1]);
    nz.u[3] = pk2(z1[2], z1[3]);
    zbf[T][PW] = nz.v;
  }
}

__global__ __launch_bounds__(64) void realnvp_fwd(
    const float* __restrict__ x, float* __restrict__ out,
    const b16x8* __restrict__ A1S, const b16x8* __restrict__ A1T,
    const b16x8* __restrict__ A2S, const b16x8* __restrict__ A2T,
    const f32x4* __restrict__ B1S, const f32x4* __restrict__ B1T,
    const f32x4* __restrict__ C2S, const f32x4* __restrict__ C2T)
{
  const int lane = threadIdx.x;          // 0..63
  const int c = lane & 15, g = lane >> 4;
  const int rowbase = blockIdx.x * 32;   // 32 rows per wave (T=2 x 16)

  f32x4 zst[2][2][2];
  b16x8 zbf[2][2];
  float rsum[2][2] = {{0.f, 0.f}, {0.f, 0.f}};
#pragma unroll
  for (int T = 0; T < 2; ++T) {
    const f32x4* xr = (const f32x4*)(x + (size_t)(rowbase + T * 16 + c) * LAT);
    const f32x4 q0 = xr[4 * g], q1 = xr[4 * g + 1], q2 = xr[4 * g + 2], q3 = xr[4 * g + 3];
    zst[T][0][0] = (f32x4){q0[0], q0[2], q1[0], q1[2]};
    zst[T][1][0] = (f32x4){q0[1], q0[3], q1[1], q1[3]};
    zst[T][0][1] = (f32x4){q2[0], q2[2], q3[0], q3[2]};
    zst[T][1][1] = (f32x4){q2[1], q2[3], q3[1], q3[3]};
#pragma unroll
    for (int p = 0; p < 2; ++p) {
      union { unsigned u[4]; b16x8 v; } zb;
      zb.u[0] = pk2(zst[T][p][0][0], zst[T][p][0][1]);
      zb.u[1] = pk2(zst[T][p][0][2], zst[T][p][0][3]);
      zb.u[2] = pk2(zst[T][p][1][0], zst[T][p][1][1]);
      zb.u[3] = pk2(zst[T][p][1][2], zst[T][p][1][3]);
      zbf[T][p] = zb.v;
    }
  }

  // Pinned software pipeline (R14: verified live by VGPR 68->116).
  FR f0 = ldfr(A1S, A1T, A2S, A2T, B1S, B1T, C2S, C2T, 0, lane);
#pragma unroll 1
  for (int lp = 0; lp < NL / 2; ++lp) {
    FR f1 = ldfr(A1S, A1T, A2S, A2T, B1S, B1T, C2S, C2T, 2 * lp + 1, lane);
    SCHED_PIN();
    layer_step<0>(f0, zst, zbf, rsum);
    const int nxt = (lp == NL / 2 - 1) ? (NL - 1) : (2 * lp + 2);  // clamp (dead last iter)
    FR f2 = ldfr(A1S, A1T, A2S, A2T, B1S, B1T, C2S, C2T, nxt, lane);
    SCHED_PIN();
    layer_step<1>(f1, zst, zbf, rsum);
    f0 = f2;
  }

#pragma unroll
  for (int T = 0; T < 2; ++T) {
    f32x4* zo = (f32x4*)(out + (size_t)(rowbase + T * 16 + c) * LAT);
    const f32x4 e0 = zst[T][0][0], o0 = zst[T][1][0];
    const f32x4 e1 = zst[T][0][1], o1 = zst[T][1][1];
    zo[4 * g]     = (f32x4){e0[0], o0[0], e0[1], o0[1]};
    zo[4 * g + 1] = (f32x4){e0[2], o0[2], e0[3], o0[3]};
    zo[4 * g + 2] = (f32x4){e1[0], o1[0], e1[1], o1[1]};
    zo[4 * g + 3] = (f32x4){e1[2], o1[2], e1[3], o1[3]};
  }
  // ld = sum(1-2r) over 512 tanh terms per row = 512 - 2*sum(r)
  float ldv[2];
#pragma unroll
  for (int T = 0; T < 2; ++T) {
    float rs = rsum[T][0] + rsum[T][1];
    rs += __shfl_xor(rs, 16, 64);
    rs += __shfl_xor(rs, 32, 64);
    ldv[T] = fmaf(-2.f, rs, 512.f);
  }
  if (g < 2)
    out[(size_t)BATCHN * LAT + rowbase + g * 16 + c] = g ? ldv[1] : ldv[0];
}

extern "C" void kernel_launch(void* const* d_in, const int* in_sizes, int n_in,
                              void* d_out, int out_size, void* d_ws, size_t ws_size,
                              hipStream_t stream) {
  const float* x   = (const float*)d_in[0];
  const float* sW1 = (const float*)d_in[1];
  const float* sb1 = (const float*)d_in[2];
  const float* sW2 = (const float*)d_in[3];
  const float* sb2 = (const float*)d_in[4];
  const float* tW1 = (const float*)d_in[5];
  const float* tb1 = (const float*)d_in[6];
  const float* tW2 = (const float*)d_in[7];
  const float* tb2 = (const float*)d_in[8];
  float* out = (float*)d_out;

  char* w = (char*)d_ws;
  b16x8* A1S = (b16x8*)w;            w += NL * 64 * sizeof(b16x8);
  b16x8* A1T = (b16x8*)w;            w += NL * 64 * sizeof(b16x8);
  b16x8* A2S = (b16x8*)w;            w += NL * 128 * sizeof(b16x8);
  b16x8* A2T = (b16x8*)w;            w += NL * 128 * sizeof(b16x8);
  f32x4* B1S = (f32x4*)w;            w += NL * 64 * sizeof(f32x4);
  f32x4* B1T = (f32x4*)w;            w += NL * 64 * sizeof(f32x4);
  f32x4* C2S = (f32x4*)w;            w += NL * 128 * sizeof(f32x4);
  f32x4* C2T = (f32x4*)w;            w += NL * 128 * sizeof(f32x4);

  hipLaunchKernelGGL(prep_frags, dim3(NL), dim3(64), 0, stream,
                     sW1, sb1, sW2, sb2, tW1, tb1, tW2, tb2,
                     A1S, A1T, A2S, A2T, B1S, B1T, C2S, C2T);
  hipLaunchKernelGGL(realnvp_fwd, dim3(BATCHN / 32), dim3(64), 0, stream,
                     x, out, A1S, A1T, A2S, A2T, B1S, B1T, C2S, C2T);
}